// Round 1
// baseline (336.452 us; speedup 1.0000x reference)
//
#include <hip/hip_runtime.h>

#define NPTS   100000
#define KCENT  1024

typedef __attribute__((ext_vector_type(8))) short bf16x8;   // 8 bf16 (4 VGPRs)
typedef __attribute__((ext_vector_type(4))) float f32x4;

__device__ __forceinline__ unsigned short f2bf(float x) {
  union { float f; unsigned u; } v; v.f = x;
  unsigned r = v.u + 0x7FFFu + ((v.u >> 16) & 1u);   // RNE
  return (unsigned short)(r >> 16);
}

// ---------------------------------------------------------------- prep
// flat items: [0,3.2M) pack features fp32->bf16 (2/thread)
//   +4096  W1T[n*72+kk] = bf16(W1[(3+kk)*64+n])   (feature rows of W1, transposed)
//   +4096  W2T[n*72+kk] = bf16(W2[kk*64+n])
//   +8192  W3T[n*72+kk] = bf16(W3[kk*128+n])
//   +1024  cent gather -> d_out[0:3072]
__global__ __launch_bounds__(256) void prep_kernel(
    const float* __restrict__ coords, const float* __restrict__ features,
    const int* __restrict__ cidx, const float* __restrict__ W1,
    const float* __restrict__ W2, const float* __restrict__ W3,
    unsigned short* __restrict__ featsBF, unsigned short* __restrict__ W1T,
    unsigned short* __restrict__ W2T, unsigned short* __restrict__ W3T,
    float* __restrict__ outCent) {
  int i = blockIdx.x * 256 + threadIdx.x;
  const int NF2 = NPTS * 64 / 2;
  if (i < NF2) {
    float2 v = ((const float2*)features)[i];
    unsigned u = ((unsigned)f2bf(v.y) << 16) | (unsigned)f2bf(v.x);
    ((unsigned*)featsBF)[i] = u;
    return;
  }
  i -= NF2;
  if (i < 4096) { int n = i >> 6, kk = i & 63; W1T[n*72+kk] = f2bf(W1[(3+kk)*64+n]); return; }
  i -= 4096;
  if (i < 4096) { int n = i >> 6, kk = i & 63; W2T[n*72+kk] = f2bf(W2[kk*64+n]); return; }
  i -= 4096;
  if (i < 8192) { int n = i >> 6, kk = i & 63; W3T[n*72+kk] = f2bf(W3[kk*128+n]); return; }
  i -= 8192;
  if (i < KCENT) {
    int ci = cidx[i];
    outCent[i*3+0] = coords[ci*3+0];
    outCent[i*3+1] = coords[ci*3+1];
    outCent[i*3+2] = coords[ci*3+2];
  }
}

// ---------------------------------------------------------------- ball query
// 1 block / centroid, 1024 threads. Ordered stream compaction of first 1024
// in-radius indices. d2 replicated in the reference's (cc+pp)-2*dot fp32 order
// (explicit _rn intrinsics: no FMA contraction).
__global__ __launch_bounds__(1024) void ballq_kernel(
    const float* __restrict__ coords, const float* __restrict__ cent,
    int* __restrict__ idxbuf, int* __restrict__ counts) {
  const int k = blockIdx.x;
  const int tid = threadIdx.x;
  const int lane = tid & 63, wid = tid >> 6;
  __shared__ int wcnt[16];
  const float cx = cent[k*3+0], cy = cent[k*3+1], cz = cent[k*3+2];
  const float cc = __fadd_rn(__fadd_rn(__fmul_rn(cx,cx), __fmul_rn(cy,cy)), __fmul_rn(cz,cz));
  int base = 0;
  for (int start = 0; start < NPTS; start += 1024) {
    int p = start + tid;
    bool sel = false;
    if (p < NPTS) {
      float px = coords[p*3+0], py = coords[p*3+1], pz = coords[p*3+2];
      float pp = __fadd_rn(__fadd_rn(__fmul_rn(px,px), __fmul_rn(py,py)), __fmul_rn(pz,pz));
      float dt = __fadd_rn(__fadd_rn(__fmul_rn(cx,px), __fmul_rn(cy,py)), __fmul_rn(cz,pz));
      float d2 = __fsub_rn(__fadd_rn(cc, pp), __fmul_rn(2.0f, dt));
      sel = (d2 <= 0.04f);
    }
    unsigned long long m = __ballot(sel);
    if (lane == 0) wcnt[wid] = __popcll(m);
    __syncthreads();
    int off = base, tot = 0;
    #pragma unroll
    for (int w = 0; w < 16; ++w) { int c = wcnt[w]; tot += c; if (w < wid) off += c; }
    int prefix = __popcll(m & ((1ull << lane) - 1ull));
    int pos = off + prefix;
    if (sel && pos < KCENT) idxbuf[(k << 10) + pos] = p;
    base += tot;
    __syncthreads();
    if (base >= KCENT) break;   // uniform
  }
  if (tid == 0) counts[k] = base < KCENT ? base : KCENT;
}

// ---------------------------------------------------------------- fused MLP + maxpool
// 1 block / centroid, 256 threads (4 waves). 16 tiles x 64 rows.
// Layer1: bf16 MFMA over 64 feature channels + fp32 VALU epilogue for rel@W1[0:3].
// Layers 2/3: bf16 MFMA. Max-pool masked by count, in registers.
// mfma_f32_16x16x32_bf16 layouts: A[m=lane&15][k=quad*8+j], B[k=quad*8+j][n=lane&15],
// C/D: col=lane&15, row=quad*4+reg.
__global__ __launch_bounds__(256, 2) void fused_kernel(
    const float* __restrict__ coords, const unsigned short* __restrict__ featsBF,
    const float* __restrict__ cent, const int* __restrict__ idxbuf,
    const int* __restrict__ counts, const float* __restrict__ W1,
    const float* __restrict__ b1, const float* __restrict__ b2,
    const float* __restrict__ b3, const unsigned short* __restrict__ gW1T,
    const unsigned short* __restrict__ gW2T, const unsigned short* __restrict__ gW3T,
    float* __restrict__ outF) {
  __shared__ __align__(16) unsigned short sW1T[64*72];
  __shared__ __align__(16) unsigned short sW2T[64*72];
  __shared__ __align__(16) unsigned short sW3T[128*72];
  __shared__ __align__(16) unsigned short sXH2[64*72];   // shared: X tile, then h2
  __shared__ __align__(16) unsigned short sH1[64*72];
  __shared__ float sRel[64*4];
  __shared__ float sW1a[3*64];
  __shared__ float sB1[64], sB2[64], sB3[128];
  __shared__ float sMax[4*128];
  __shared__ float sCent[3];

  const int k = blockIdx.x;
  const int tid = threadIdx.x;
  const int w = tid >> 6;
  const int lane = tid & 63;
  const int quad = lane >> 4;
  const int cl = lane & 15;

  for (int i = tid; i < 576; i += 256)  ((uint4*)sW1T)[i] = ((const uint4*)gW1T)[i];
  for (int i = tid; i < 576; i += 256)  ((uint4*)sW2T)[i] = ((const uint4*)gW2T)[i];
  for (int i = tid; i < 1152; i += 256) ((uint4*)sW3T)[i] = ((const uint4*)gW3T)[i];
  if (tid < 192) sW1a[tid] = W1[tid];          // rows 0..2 of W1, [j][o]
  if (tid < 64)  sB1[tid] = b1[tid];
  if (tid < 64)  sB2[tid] = b2[tid];
  if (tid < 128) sB3[tid] = b3[tid];
  if (tid < 3)   sCent[tid] = cent[k*3+tid];
  const int count = counts[k];
  __syncthreads();

  float runmax[8];
  #pragma unroll
  for (int i = 0; i < 8; ++i) runmax[i] = -__builtin_inff();

  const int r = tid >> 2;     // staging row 0..63
  const int sub = tid & 3;

  for (int tile = 0; tile < 16; ++tile) {
    const int rowbase = tile << 6;

    { // ---- stage X (features bf16) + rel (fp32) ----
      int j = rowbase + r;
      int p = (j < count) ? idxbuf[(k << 10) + j] : 0;
      const uint4* fp = (const uint4*)(featsBF + p*64 + sub*16);
      uint4 a = fp[0], b = fp[1];
      uint4* xd = (uint4*)(sXH2 + r*72 + sub*16);
      xd[0] = a; xd[1] = b;
      if (sub == 0) {
        sRel[r*4+0] = coords[p*3+0] - sCent[0];
        sRel[r*4+1] = coords[p*3+1] - sCent[1];
        sRel[r*4+2] = coords[p*3+2] - sCent[2];
      }
    }
    __syncthreads();   // A

    { // ---- GEMM1 (features @ W1[3:67]) + rel/bias/relu epilogue -> sH1 ----
      f32x4 acc[4];
      #pragma unroll
      for (int nt = 0; nt < 4; ++nt) acc[nt] = (f32x4){0.f,0.f,0.f,0.f};
      #pragma unroll
      for (int ks = 0; ks < 2; ++ks) {
        int kb = ks*32 + quad*8;
        bf16x8 a = *(const bf16x8*)(sXH2 + (w*16+cl)*72 + kb);
        #pragma unroll
        for (int nt = 0; nt < 4; ++nt) {
          bf16x8 b = *(const bf16x8*)(sW1T + (nt*16+cl)*72 + kb);
          acc[nt] = __builtin_amdgcn_mfma_f32_16x16x32_bf16(a, b, acc[nt], 0, 0, 0);
        }
      }
      float w0[4], w1[4], w2[4], bb[4];
      #pragma unroll
      for (int nt = 0; nt < 4; ++nt) {
        w0[nt] = sW1a[      nt*16+cl];
        w1[nt] = sW1a[ 64 + nt*16+cl];
        w2[nt] = sW1a[128 + nt*16+cl];
        bb[nt] = sB1[nt*16+cl];
      }
      #pragma unroll
      for (int reg = 0; reg < 4; ++reg) {
        int row = w*16 + quad*4 + reg;
        float rx = sRel[row*4+0], ry = sRel[row*4+1], rz = sRel[row*4+2];
        #pragma unroll
        for (int nt = 0; nt < 4; ++nt) {
          float v = acc[nt][reg] + bb[nt] + rx*w0[nt] + ry*w1[nt] + rz*w2[nt];
          sH1[row*72 + nt*16+cl] = f2bf(fmaxf(v, 0.f));
        }
      }
    }
    __syncthreads();   // B

    { // ---- GEMM2 -> relu -> sXH2 (as h2) ----
      f32x4 acc[4];
      #pragma unroll
      for (int nt = 0; nt < 4; ++nt) acc[nt] = (f32x4){0.f,0.f,0.f,0.f};
      #pragma unroll
      for (int ks = 0; ks < 2; ++ks) {
        int kb = ks*32 + quad*8;
        bf16x8 a = *(const bf16x8*)(sH1 + (w*16+cl)*72 + kb);
        #pragma unroll
        for (int nt = 0; nt < 4; ++nt) {
          bf16x8 b = *(const bf16x8*)(sW2T + (nt*16+cl)*72 + kb);
          acc[nt] = __builtin_amdgcn_mfma_f32_16x16x32_bf16(a, b, acc[nt], 0, 0, 0);
        }
      }
      float bb[4];
      #pragma unroll
      for (int nt = 0; nt < 4; ++nt) bb[nt] = sB2[nt*16+cl];
      #pragma unroll
      for (int reg = 0; reg < 4; ++reg) {
        int row = w*16 + quad*4 + reg;
        #pragma unroll
        for (int nt = 0; nt < 4; ++nt)
          sXH2[row*72 + nt*16+cl] = f2bf(fmaxf(acc[nt][reg] + bb[nt], 0.f));
      }
    }
    __syncthreads();   // C

    { // ---- GEMM3 -> relu -> masked running max ----
      f32x4 acc[8];
      #pragma unroll
      for (int nt = 0; nt < 8; ++nt) acc[nt] = (f32x4){0.f,0.f,0.f,0.f};
      #pragma unroll
      for (int ks = 0; ks < 2; ++ks) {
        int kb = ks*32 + quad*8;
        bf16x8 a = *(const bf16x8*)(sXH2 + (w*16+cl)*72 + kb);
        #pragma unroll
        for (int nt = 0; nt < 8; ++nt) {
          bf16x8 b = *(const bf16x8*)(sW3T + (nt*16+cl)*72 + kb);
          acc[nt] = __builtin_amdgcn_mfma_f32_16x16x32_bf16(a, b, acc[nt], 0, 0, 0);
        }
      }
      float bb[8];
      #pragma unroll
      for (int nt = 0; nt < 8; ++nt) bb[nt] = sB3[nt*16+cl];
      #pragma unroll
      for (int reg = 0; reg < 4; ++reg) {
        bool valid = (rowbase + w*16 + quad*4 + reg) < count;
        if (valid) {
          #pragma unroll
          for (int nt = 0; nt < 8; ++nt) {
            float v = fmaxf(acc[nt][reg] + bb[nt], 0.f);
            runmax[nt] = fmaxf(runmax[nt], v);
          }
        }
      }
    }
    __syncthreads();   // D (protects sXH2 reads vs next tile's stage)
  }

  // ---- reduce: quads -> wave, waves -> block ----
  #pragma unroll
  for (int nt = 0; nt < 8; ++nt) {
    float m = runmax[nt];
    m = fmaxf(m, __shfl_xor(m, 16));
    m = fmaxf(m, __shfl_xor(m, 32));
    if (quad == 0) sMax[w*128 + nt*16 + cl] = m;
  }
  __syncthreads();
  if (tid < 128) {
    float v = fmaxf(fmaxf(sMax[tid], sMax[128+tid]),
                    fmaxf(sMax[256+tid], sMax[384+tid]));
    outF[k*128 + tid] = v;
  }
}

// ---------------------------------------------------------------- launch
extern "C" void kernel_launch(void* const* d_in, const int* in_sizes, int n_in,
                              void* d_out, int out_size, void* d_ws, size_t ws_size,
                              hipStream_t stream) {
  const float* coords   = (const float*)d_in[0];
  const float* features = (const float*)d_in[1];
  const int*   cidx     = (const int*)d_in[2];
  const float* W1 = (const float*)d_in[3];
  const float* b1 = (const float*)d_in[4];
  const float* W2 = (const float*)d_in[5];
  const float* b2 = (const float*)d_in[6];
  const float* W3 = (const float*)d_in[7];
  const float* b3 = (const float*)d_in[8];
  float* out = (float*)d_out;           // [0:3072) cent, [3072:) new_features

  char* ws = (char*)d_ws;
  unsigned short* featsBF = (unsigned short*)ws;                 // 12,800,000 B
  unsigned short* W1T = (unsigned short*)(ws + 12800000);        // 9,216 B
  unsigned short* W2T = (unsigned short*)(ws + 12809216);        // 9,216 B
  unsigned short* W3T = (unsigned short*)(ws + 12818432);        // 18,432 B
  int* idxbuf = (int*)(ws + 12836864);                           // 4,194,304 B
  int* counts = (int*)(ws + 17031168);                           // 4,096 B

  prep_kernel<<<12568, 256, 0, stream>>>(coords, features, cidx, W1, W2, W3,
                                         featsBF, W1T, W2T, W3T, out);
  ballq_kernel<<<KCENT, 1024, 0, stream>>>(coords, out, idxbuf, counts);
  fused_kernel<<<KCENT, 256, 0, stream>>>(coords, featsBF, out, idxbuf, counts,
                                          W1, b1, b2, b3, W1T, W2T, W3T, out + 3072);
}

// Round 2
// 292.973 us; speedup vs baseline: 1.1484x; 1.1484x over previous
//
#include <hip/hip_runtime.h>
#include <hip/hip_bf16.h>

#define NPTS   100000
#define KCENT  1024
#define NWORDS 1564          // ceil-ish: 391 blocks * 4 waves of 64 points
#define WSTRIDE 1600         // mask words per centroid (padded)

typedef __attribute__((ext_vector_type(8))) short bf16x8;   // 8 bf16 (4 VGPRs)
typedef __attribute__((ext_vector_type(4))) float f32x4;
typedef unsigned long long u64;

__device__ __forceinline__ unsigned short f2bf(float x) {
  union { float f; unsigned u; } v; v.f = x;
  unsigned r = v.u + 0x7FFFu + ((v.u >> 16) & 1u);   // RNE
  return (unsigned short)(r >> 16);
}

__device__ __forceinline__ unsigned pk2bf(float a, float b) {
  union { __hip_bfloat162 h; unsigned u; } cv;
  cv.h = __float22bfloat162_rn(make_float2(a, b));
  return cv.u;
}

__device__ __forceinline__ bf16x8 pack_bf8(f32x4 a, f32x4 b) {
  union { bf16x8 v; unsigned u[4]; } r;
  r.u[0] = pk2bf(a[0], a[1]);
  r.u[1] = pk2bf(a[2], a[3]);
  r.u[2] = pk2bf(b[0], b[1]);
  r.u[3] = pk2bf(b[2], b[3]);
  return r.v;
}

// ---------------------------------------------------------------- prep
// W1T[n*72+kk] = bf16(W1[(3+kk)*64+n])  (feature rows of W1, transposed)
// W2T[n*72+kk] = bf16(W2[kk*64+n])
// W3T[n*72+kk] = bf16(W3[kk*128+n])
// cent gather -> d_out[0:3072)
__global__ __launch_bounds__(256) void prep_kernel(
    const float* __restrict__ coords, const int* __restrict__ cidx,
    const float* __restrict__ W1, const float* __restrict__ W2,
    const float* __restrict__ W3,
    unsigned short* __restrict__ W1T, unsigned short* __restrict__ W2T,
    unsigned short* __restrict__ W3T, float* __restrict__ outCent) {
  int i = blockIdx.x * 256 + threadIdx.x;
  if (i < 4096) { int n = i >> 6, kk = i & 63; W1T[n*72+kk] = f2bf(W1[(3+kk)*64+n]); return; }
  i -= 4096;
  if (i < 4096) { int n = i >> 6, kk = i & 63; W2T[n*72+kk] = f2bf(W2[kk*64+n]); return; }
  i -= 4096;
  if (i < 8192) { int n = i >> 6, kk = i & 63; W3T[n*72+kk] = f2bf(W3[kk*128+n]); return; }
  i -= 8192;
  if (i < KCENT) {
    int ci = cidx[i];
    outCent[i*3+0] = coords[ci*3+0];
    outCent[i*3+1] = coords[ci*3+1];
    outCent[i*3+2] = coords[ci*3+2];
  }
}

// ---------------------------------------------------------------- mask build
// grid (391, 64): x = 256-point segment, y = 16-centroid group. Barrier-free
// ballot per (wave, centroid) -> one 64-bit mask word. Same d2 arithmetic
// chain as the round-1 passing kernel (no FMA contraction).
__global__ __launch_bounds__(256) void maskbuild_kernel(
    const float* __restrict__ coords, const float* __restrict__ cent,
    u64* __restrict__ maskbuf) {
  __shared__ float sC[48];
  __shared__ float sCC[16];
  const int tid = threadIdx.x;
  const int bx = blockIdx.x, by = blockIdx.y;
  if (tid < 48) sC[tid] = cent[by*48 + tid];
  __syncthreads();
  if (tid < 16) {
    float x = sC[tid*3], y = sC[tid*3+1], z = sC[tid*3+2];
    sCC[tid] = __fadd_rn(__fadd_rn(__fmul_rn(x,x), __fmul_rn(y,y)), __fmul_rn(z,z));
  }
  const int p = bx*256 + tid;
  const bool inr = p < NPTS;
  float px = 0.f, py = 0.f, pz = 0.f;
  if (inr) { px = coords[p*3]; py = coords[p*3+1]; pz = coords[p*3+2]; }
  const float pp = __fadd_rn(__fadd_rn(__fmul_rn(px,px), __fmul_rn(py,py)), __fmul_rn(pz,pz));
  __syncthreads();
  const int wid = tid >> 6;
  u64* outw = maskbuf + (u64)(by*16)*WSTRIDE + bx*4 + wid;
  #pragma unroll
  for (int ci = 0; ci < 16; ++ci) {
    float cx = sC[ci*3], cy = sC[ci*3+1], cz = sC[ci*3+2];
    float dt = __fadd_rn(__fadd_rn(__fmul_rn(cx,px), __fmul_rn(cy,py)), __fmul_rn(cz,pz));
    float d2 = __fsub_rn(__fadd_rn(sCC[ci], pp), __fmul_rn(2.0f, dt));
    bool sel = inr && (d2 <= 0.04f);
    u64 m = __ballot(sel);
    if ((tid & 63) == 0) outw[(u64)ci * WSTRIDE] = m;
  }
}

// ---------------------------------------------------------------- mask scan
// One wave per centroid: ordered compaction of the first 1024 set bits.
// shfl prefix over lane popcounts, early uniform exit, next-chunk prefetch.
__global__ __launch_bounds__(256) void maskscan_kernel(
    const u64* __restrict__ maskbuf, int* __restrict__ idxbuf,
    int* __restrict__ counts) {
  const int tid = threadIdx.x;
  const int lane = tid & 63;
  const int c = blockIdx.x*4 + (tid >> 6);
  const u64* M = maskbuf + (u64)c * WSTRIDE;
  int* out = idxbuf + (c << 10);
  int base = 0;
  u64 word = (lane < NWORDS) ? M[lane] : 0ull;
  for (int chunk = 0; chunk < 25; ++chunk) {
    u64 next = 0ull;
    int wn = (chunk+1)*64 + lane;
    if (chunk+1 < 25 && wn < NWORDS) next = M[wn];
    int pc = __popcll(word);
    int inc = pc;
    #pragma unroll
    for (int d = 1; d < 64; d <<= 1) {
      int t = __shfl_up(inc, d);
      if (lane >= d) inc += t;
    }
    int tot = __shfl(inc, 63);
    int pos = base + inc - pc;
    while (word != 0ull && pos < KCENT) {
      int b = __ffsll((unsigned long long)word) - 1;
      out[pos++] = chunk*4096 + lane*64 + b;
      word &= word - 1ull;
    }
    base += tot;
    if (base >= KCENT) break;    // uniform (tot broadcast)
    word = next;
  }
  if (lane == 0) counts[c] = base < KCENT ? base : KCENT;
}

// ---------------------------------------------------------------- fused MLP + maxpool
// Transposed-operand scheme: A = weights (hoisted to VGPR), B = activations.
// D layout: m = out-channel = nt*16 + q*4 + reg, n = point-row = cl.
// => epilogue writes are contiguous b64, next-layer B reads contiguous b128,
//    rel/validity are per-lane (row = cl). Wave-private h-buffer, NO barriers
//    in the strip loop. b3 + final relu deferred past the max-pool.
__global__ __launch_bounds__(256, 2) void fused_kernel(
    const float* __restrict__ coords, const float* __restrict__ features,
    const float* __restrict__ cent, const int* __restrict__ idxbuf,
    const int* __restrict__ counts,
    const float* __restrict__ W1, const float* __restrict__ b1,
    const float* __restrict__ b2, const float* __restrict__ b3,
    const unsigned short* __restrict__ gW1T, const unsigned short* __restrict__ gW2T,
    const unsigned short* __restrict__ gW3T, float* __restrict__ outF) {
  __shared__ float sW1a[192];            // W1 rows 0..2 (rel part), fp32
  __shared__ float sB1[64], sB2[64];
  __shared__ float sMax[512];
  __shared__ __align__(16) unsigned short sH[4*1152];   // per-wave 16x72 h-buf

  const int k = blockIdx.x, tid = threadIdx.x;
  const int w = tid >> 6, lane = tid & 63;
  const int q = lane >> 4, cl = lane & 15;

  if (tid < 192) sW1a[tid] = W1[tid];
  if (tid < 64)  sB1[tid] = b1[tid];
  if (tid >= 64 && tid < 128) sB2[tid-64] = b2[tid-64];

  // hoist all weight fragments (A-operand layout: lane holds W T[nt*16+cl][k])
  bf16x8 w1f[4][2], w2f[4][2], w3f[8][2];
  #pragma unroll
  for (int nt = 0; nt < 4; ++nt)
    #pragma unroll
    for (int ks = 0; ks < 2; ++ks) {
      w1f[nt][ks] = *(const bf16x8*)(gW1T + (nt*16+cl)*72 + ks*32 + q*8);
      w2f[nt][ks] = *(const bf16x8*)(gW2T + (nt*16+cl)*72 + ks*32 + q*8);
    }
  #pragma unroll
  for (int nt = 0; nt < 8; ++nt)
    #pragma unroll
    for (int ks = 0; ks < 2; ++ks)
      w3f[nt][ks] = *(const bf16x8*)(gW3T + (nt*16+cl)*72 + ks*32 + q*8);

  const int count = counts[k];
  const float cx = cent[k*3], cy = cent[k*3+1], cz = cent[k*3+2];
  unsigned short* myH = sH + w*1152;
  __syncthreads();

  f32x4 runmax[8];
  #pragma unroll
  for (int i = 0; i < 8; ++i)
    runmax[i] = (f32x4){-__builtin_inff(), -__builtin_inff(),
                        -__builtin_inff(), -__builtin_inff()};

  const int nstrips = (count + 15) >> 4;      // uniform per block
  for (int s = w; s < nstrips; s += 4) {
    const int j = (s << 4) + cl;              // this lane's point-row
    const bool valid = j < count;
    int p = idxbuf[(k << 10) + j];
    p = valid ? p : 0;
    const float rx = coords[p*3]   - cx;
    const float ry = coords[p*3+1] - cy;
    const float rz = coords[p*3+2] - cz;

    // X B-fragments: fp32 features -> bf16 in-flight
    bf16x8 xb[2];
    #pragma unroll
    for (int ks = 0; ks < 2; ++ks) {
      const float* fp = features + p*64 + ks*32 + q*8;
      f32x4 f0 = *(const f32x4*)fp;
      f32x4 f1 = *(const f32x4*)(fp + 4);
      xb[ks] = pack_bf8(f0, f1);
    }

    // ---- layer 1 ----
    f32x4 acc[4];
    #pragma unroll
    for (int nt = 0; nt < 4; ++nt) acc[nt] = (f32x4){0.f,0.f,0.f,0.f};
    #pragma unroll
    for (int ks = 0; ks < 2; ++ks)
      #pragma unroll
      for (int nt = 0; nt < 4; ++nt)
        acc[nt] = __builtin_amdgcn_mfma_f32_16x16x32_bf16(w1f[nt][ks], xb[ks], acc[nt], 0, 0, 0);
    #pragma unroll
    for (int nt = 0; nt < 4; ++nt) {
      const int o = nt*16 + q*4;
      f32x4 bb = *(const f32x4*)(sB1 + o);          // broadcast LDS reads
      f32x4 a0 = *(const f32x4*)(sW1a + o);
      f32x4 a1 = *(const f32x4*)(sW1a + 64 + o);
      f32x4 a2 = *(const f32x4*)(sW1a + 128 + o);
      float v[4];
      #pragma unroll
      for (int r = 0; r < 4; ++r) {
        float t = acc[nt][r] + bb[r] + rx*a0[r] + ry*a1[r] + rz*a2[r];
        v[r] = fmaxf(t, 0.f);
      }
      uint2 pk = { pk2bf(v[0], v[1]), pk2bf(v[2], v[3]) };
      *(uint2*)(myH + cl*72 + o) = pk;              // contiguous b64
    }

    // ---- layer 2 (reads h1 fully into regs before overwriting with h2) ----
    bf16x8 hb[2];
    #pragma unroll
    for (int ks = 0; ks < 2; ++ks)
      hb[ks] = *(const bf16x8*)(myH + cl*72 + ks*32 + q*8);   // contiguous b128
    #pragma unroll
    for (int nt = 0; nt < 4; ++nt) acc[nt] = (f32x4){0.f,0.f,0.f,0.f};
    #pragma unroll
    for (int ks = 0; ks < 2; ++ks)
      #pragma unroll
      for (int nt = 0; nt < 4; ++nt)
        acc[nt] = __builtin_amdgcn_mfma_f32_16x16x32_bf16(w2f[nt][ks], hb[ks], acc[nt], 0, 0, 0);
    #pragma unroll
    for (int nt = 0; nt < 4; ++nt) {
      const int o = nt*16 + q*4;
      f32x4 bb = *(const f32x4*)(sB2 + o);
      float v[4];
      #pragma unroll
      for (int r = 0; r < 4; ++r) v[r] = fmaxf(acc[nt][r] + bb[r], 0.f);
      uint2 pk = { pk2bf(v[0], v[1]), pk2bf(v[2], v[3]) };
      *(uint2*)(myH + cl*72 + o) = pk;
    }

    // ---- layer 3 + masked running max (bias deferred) ----
    bf16x8 h2b[2];
    #pragma unroll
    for (int ks = 0; ks < 2; ++ks)
      h2b[ks] = *(const bf16x8*)(myH + cl*72 + ks*32 + q*8);
    f32x4 acc3[8];
    #pragma unroll
    for (int nt = 0; nt < 8; ++nt) acc3[nt] = (f32x4){0.f,0.f,0.f,0.f};
    #pragma unroll
    for (int ks = 0; ks < 2; ++ks)
      #pragma unroll
      for (int nt = 0; nt < 8; ++nt)
        acc3[nt] = __builtin_amdgcn_mfma_f32_16x16x32_bf16(w3f[nt][ks], h2b[ks], acc3[nt], 0, 0, 0);
    const float vm = valid ? 0.f : -__builtin_inff();
    #pragma unroll
    for (int nt = 0; nt < 8; ++nt)
      #pragma unroll
      for (int r = 0; r < 4; ++r)
        runmax[nt][r] = fmaxf(runmax[nt][r], acc3[nt][r] + vm);
  }

  // reduce over cl (16 row-groups) within each quad, then across waves
  #pragma unroll
  for (int nt = 0; nt < 8; ++nt) {
    #pragma unroll
    for (int r = 0; r < 4; ++r) {
      float m = runmax[nt][r];
      m = fmaxf(m, __shfl_xor(m, 1));
      m = fmaxf(m, __shfl_xor(m, 2));
      m = fmaxf(m, __shfl_xor(m, 4));
      m = fmaxf(m, __shfl_xor(m, 8));
      runmax[nt][r] = m;
    }
    if (cl == 0) *(f32x4*)(sMax + w*128 + nt*16 + q*4) = runmax[nt];
  }
  __syncthreads();
  if (tid < 128) {
    float m = fmaxf(fmaxf(sMax[tid], sMax[128+tid]),
                    fmaxf(sMax[256+tid], sMax[384+tid]));
    outF[k*128 + tid] = fmaxf(m + b3[tid], 0.f);
  }
}

// ---------------------------------------------------------------- launch
extern "C" void kernel_launch(void* const* d_in, const int* in_sizes, int n_in,
                              void* d_out, int out_size, void* d_ws, size_t ws_size,
                              hipStream_t stream) {
  const float* coords   = (const float*)d_in[0];
  const float* features = (const float*)d_in[1];
  const int*   cidx     = (const int*)d_in[2];
  const float* W1 = (const float*)d_in[3];
  const float* b1 = (const float*)d_in[4];
  const float* W2 = (const float*)d_in[5];
  const float* b2 = (const float*)d_in[6];
  const float* W3 = (const float*)d_in[7];
  const float* b3 = (const float*)d_in[8];
  float* out = (float*)d_out;           // [0:3072) cent, [3072:) new_features

  char* ws = (char*)d_ws;
  unsigned short* W1T = (unsigned short*)(ws + 0);          //  9,216 B
  unsigned short* W2T = (unsigned short*)(ws + 9216);       //  9,216 B
  unsigned short* W3T = (unsigned short*)(ws + 18432);      // 18,432 B
  u64* maskbuf = (u64*)(ws + 36864);                        // 13,107,200 B
  int* idxbuf  = (int*)(ws + 36864 + 13107200);             //  4,194,304 B
  int* counts  = (int*)(ws + 36864 + 13107200 + 4194304);   //  4,096 B

  prep_kernel<<<68, 256, 0, stream>>>(coords, cidx, W1, W2, W3,
                                      W1T, W2T, W3T, out);
  maskbuild_kernel<<<dim3(391, 64), 256, 0, stream>>>(coords, out, maskbuf);
  maskscan_kernel<<<256, 256, 0, stream>>>(maskbuf, idxbuf, counts);
  fused_kernel<<<KCENT, 256, 0, stream>>>(coords, features, out, idxbuf, counts,
                                          W1, b1, b2, b3, W1T, W2T, W3T,
                                          out + 3072);
}

// Round 3
// 290.006 us; speedup vs baseline: 1.1602x; 1.0102x over previous
//
#include <hip/hip_runtime.h>
#include <hip/hip_bf16.h>

#define NPTS    100000
#define KCENT   1024
#define NSEG    391          // ceil(NPTS/256)
#define NWORDS  1564         // NSEG*4 words of 64 points
#define WSTRIDE 1600         // mask words per centroid (padded)

typedef __attribute__((ext_vector_type(8))) short bf16x8;   // 8 bf16 (4 VGPRs)
typedef __attribute__((ext_vector_type(4))) float f32x4;
typedef unsigned long long u64;

__device__ __forceinline__ unsigned short f2bf(float x) {
  union { float f; unsigned u; } v; v.f = x;
  unsigned r = v.u + 0x7FFFu + ((v.u >> 16) & 1u);   // RNE
  return (unsigned short)(r >> 16);
}
__device__ __forceinline__ unsigned pk2bf(float a, float b) {
  union { __hip_bfloat162 h; unsigned u; } cv;
  cv.h = __float22bfloat162_rn(make_float2(a, b));
  return cv.u;
}
__device__ __forceinline__ bf16x8 pack_bf8(f32x4 a, f32x4 b) {
  union { bf16x8 v; unsigned u[4]; } r;
  r.u[0] = pk2bf(a[0], a[1]); r.u[1] = pk2bf(a[2], a[3]);
  r.u[2] = pk2bf(b[0], b[1]); r.u[3] = pk2bf(b[2], b[3]);
  return r.v;
}

// ---------------------------------------------------------------- mask build
// grid (NSEG, 32): x = 256-point segment, y = 32-centroid group. Self-gathers
// centroid coords (no prep dependency -> maskbuf may alias prep outputs).
// Same fp32 d2 chain as the round-1/2 passing kernels.
__global__ __launch_bounds__(256) void maskbuild_kernel(
    const float* __restrict__ coords, const int* __restrict__ cidx,
    u64* __restrict__ maskbuf) {
  __shared__ float sC[96];
  __shared__ float sCC[32];
  const int tid = threadIdx.x;
  const int bx = blockIdx.x, by = blockIdx.y;
  if (tid < 96) sC[tid] = coords[cidx[by*32 + tid/3]*3 + tid%3];
  __syncthreads();
  if (tid < 32) {
    float x = sC[tid*3], y = sC[tid*3+1], z = sC[tid*3+2];
    sCC[tid] = __fadd_rn(__fadd_rn(__fmul_rn(x,x), __fmul_rn(y,y)), __fmul_rn(z,z));
  }
  const int p = bx*256 + tid;
  const bool inr = p < NPTS;
  float px = 0.f, py = 0.f, pz = 0.f;
  if (inr) { px = coords[p*3]; py = coords[p*3+1]; pz = coords[p*3+2]; }
  const float pp = __fadd_rn(__fadd_rn(__fmul_rn(px,px), __fmul_rn(py,py)), __fmul_rn(pz,pz));
  __syncthreads();
  const int lane = tid & 63, wid = tid >> 6;
  u64 myw = 0ull;
  #pragma unroll
  for (int ci = 0; ci < 32; ++ci) {
    float cx = sC[ci*3], cy = sC[ci*3+1], cz = sC[ci*3+2];
    float dt = __fadd_rn(__fadd_rn(__fmul_rn(cx,px), __fmul_rn(cy,py)), __fmul_rn(cz,pz));
    float d2 = __fsub_rn(__fadd_rn(sCC[ci], pp), __fmul_rn(2.0f, dt));
    bool sel = inr && (d2 <= 0.04f);
    u64 m = __ballot(sel);
    if (lane == ci) myw = m;
  }
  if (lane < 32)
    maskbuf[(u64)(by*32 + lane)*WSTRIDE + bx*4 + wid] = myw;
}

// ---------------------------------------------------------------- mask scan
// One wave per centroid: ordered compaction of first 1024 set bits.
__global__ __launch_bounds__(256) void maskscan_kernel(
    const u64* __restrict__ maskbuf, int* __restrict__ idxbuf,
    int* __restrict__ counts) {
  const int tid = threadIdx.x;
  const int lane = tid & 63;
  const int c = blockIdx.x*4 + (tid >> 6);
  const u64* M = maskbuf + (u64)c * WSTRIDE;
  int* out = idxbuf + (c << 10);
  int base = 0;
  u64 word = (lane < NWORDS) ? M[lane] : 0ull;
  for (int chunk = 0; chunk < 25; ++chunk) {
    u64 next = 0ull;
    int wn = (chunk+1)*64 + lane;
    if (chunk+1 < 25 && wn < NWORDS) next = M[wn];
    int pc = __popcll(word);
    int inc = pc;
    #pragma unroll
    for (int d = 1; d < 64; d <<= 1) {
      int t = __shfl_up(inc, d);
      if (lane >= d) inc += t;
    }
    int tot = __shfl(inc, 63);
    int pos = base + inc - pc;
    while (word != 0ull && pos < KCENT) {
      int b = __ffsll((unsigned long long)word) - 1;
      out[pos++] = chunk*4096 + lane*64 + b;
      word &= word - 1ull;
    }
    base += tot;
    if (base >= KCENT) break;    // uniform
    word = next;
  }
  if (lane == 0) counts[c] = base < KCENT ? base : KCENT;
}

// ---------------------------------------------------------------- prep
// featsBF (bf16), coords4 (float4-padded), W1T 64x96 augmented
// (k<64: W1 feat rows; k=64..66: W1 rel rows; k=67: b1; else 0),
// W2T/W3T 72-stride transposed, cent gather -> d_out[0:3072).
// Runs AFTER maskscan so featsBF/coords4 may alias maskbuf.
__global__ __launch_bounds__(256) void prep_kernel(
    const float* __restrict__ coords, const float* __restrict__ features,
    const int* __restrict__ cidx, const float* __restrict__ W1,
    const float* __restrict__ b1, const float* __restrict__ W2,
    const float* __restrict__ W3,
    unsigned short* __restrict__ featsBF, f32x4* __restrict__ coords4,
    unsigned short* __restrict__ W1T, unsigned short* __restrict__ W2T,
    unsigned short* __restrict__ W3T, float* __restrict__ outCent) {
  int i = blockIdx.x * 256 + threadIdx.x;
  if (i < 800000) {                       // 8 feature floats -> bf16x8
    const f32x4* src = (const f32x4*)features + i*2;
    f32x4 f0 = src[0], f1 = src[1];
    union { bf16x8 v; uint4 u; } pk; pk.v = pack_bf8(f0, f1);
    ((uint4*)featsBF)[i] = pk.u;
    return;
  }
  i -= 800000;
  if (i < NPTS) {
    coords4[i] = (f32x4){coords[3*i], coords[3*i+1], coords[3*i+2], 0.f};
    return;
  }
  i -= NPTS;
  if (i < 6144) {                         // W1T augmented, stride 96
    int n = i / 96, kk = i - n*96;
    float v = 0.f;
    if (kk < 64)      v = W1[(3+kk)*64 + n];
    else if (kk < 67) v = W1[(kk-64)*64 + n];
    else if (kk == 67) v = b1[n];
    W1T[n*96 + kk] = f2bf(v);
    return;
  }
  i -= 6144;
  if (i < 4608) { int n = i / 72, kk = i - n*72;
    W2T[n*72 + kk] = f2bf(kk < 64 ? W2[kk*64 + n] : 0.f); return; }
  i -= 4608;
  if (i < 9216) { int n = i / 72, kk = i - n*72;
    W3T[n*72 + kk] = f2bf(kk < 64 ? W3[kk*128 + n] : 0.f); return; }
  i -= 9216;
  if (i < KCENT) {
    int ci = cidx[i];
    outCent[i*3+0] = coords[ci*3+0];
    outCent[i*3+1] = coords[ci*3+1];
    outCent[i*3+2] = coords[ci*3+2];
  }
}

// ---------------------------------------------------------------- fused MLP + maxpool
// 2 blocks/centroid (strips interleaved mod 2), 4 waves each, strips of 16
// points. Weights = MFMA A operand (W1/W3 frags in regs, W2 re-read from LDS
// to stay <=256 unified regs = 2 waves/SIMD). Depth-2 idx / depth-1 feature
// prefetch pipeline. rel + b1 folded into layer-1 MFMA via K=96. b3 + final
// relu deferred to combine kernel.
__global__ __launch_bounds__(256, 2) void fused_kernel(
    const unsigned short* __restrict__ featsBF, const f32x4* __restrict__ coords4,
    const float* __restrict__ cent, const int* __restrict__ idxbuf,
    const int* __restrict__ counts, const float* __restrict__ b2v,
    const unsigned short* __restrict__ gW1T, const unsigned short* __restrict__ gW2T,
    const unsigned short* __restrict__ gW3T, float* __restrict__ pmax) {
  __shared__ __align__(16) unsigned short sW2T[64*72];
  __shared__ __align__(16) unsigned short sH[4*16*72];   // per-wave h-buf
  __shared__ float sB2[64];
  __shared__ float sMax[512];

  const int bx = blockIdx.x;
  const int k = bx >> 1, b = bx & 1;
  const int tid = threadIdx.x;
  const int w = tid >> 6, lane = tid & 63;
  const int q = lane >> 4, cl = lane & 15;

  for (int i = tid; i < 576; i += 256) ((uint4*)sW2T)[i] = ((const uint4*)gW2T)[i];
  if (tid < 64) sB2[tid] = b2v[tid];

  bf16x8 w1f[3][4], w3f[2][8];
  #pragma unroll
  for (int ks = 0; ks < 3; ++ks)
    #pragma unroll
    for (int nt = 0; nt < 4; ++nt)
      w1f[ks][nt] = *(const bf16x8*)(gW1T + (nt*16+cl)*96 + ks*32 + q*8);
  #pragma unroll
  for (int ks = 0; ks < 2; ++ks)
    #pragma unroll
    for (int nt = 0; nt < 8; ++nt)
      w3f[ks][nt] = *(const bf16x8*)(gW3T + (nt*16+cl)*72 + ks*32 + q*8);

  const int count = counts[k];
  const float cx = cent[k*3], cy = cent[k*3+1], cz = cent[k*3+2];
  unsigned short* myH = sH + w*1152;
  const int kb = k << 10;
  __syncthreads();

  f32x4 runmax[8];
  #pragma unroll
  for (int i = 0; i < 8; ++i)
    runmax[i] = (f32x4){-__builtin_inff(), -__builtin_inff(),
                        -__builtin_inff(), -__builtin_inff()};

  const int nstrips = (count + 15) >> 4;
  int t = 2*w + b;

  // ---- pipeline preload: idx(t), feats(t) issued; idx(t+8) issued ----
  int p_cur = 0;
  if (t < nstrips) { int j = t*16 + cl; if (j < count) p_cur = idxbuf[kb + j]; }
  f32x4  c4  = coords4[p_cur];
  bf16x8 xf0 = *(const bf16x8*)(featsBF + p_cur*64 + q*8);
  bf16x8 xf1 = *(const bf16x8*)(featsBF + p_cur*64 + 32 + q*8);
  int p_nxt = 0;
  { int tn = t + 8;
    if (tn < nstrips) { int j = tn*16 + cl; if (j < count) p_nxt = idxbuf[kb + j]; } }

  for (; t < nstrips; t += 8) {
    // prefetch: idx two strips ahead, feats one strip ahead (p_nxt resident)
    int p_nn = 0;
    { int tnn = t + 16;
      if (tnn < nstrips) { int j = tnn*16 + cl; if (j < count) p_nn = idxbuf[kb + j]; } }
    f32x4  c4n  = coords4[p_nxt];
    bf16x8 xf0n = *(const bf16x8*)(featsBF + p_nxt*64 + q*8);
    bf16x8 xf1n = *(const bf16x8*)(featsBF + p_nxt*64 + 32 + q*8);

    // rel/bias B-fragment for K-block 2 (k=64..67: rx,ry,rz,1; rest 0)
    const float rx = c4[0] - cx, ry = c4[1] - cy, rz = c4[2] - cz;
    union { bf16x8 v; unsigned u[4]; } rf;
    rf.u[0] = pk2bf(rx, ry); rf.u[1] = pk2bf(rz, 1.0f);
    rf.u[2] = 0u; rf.u[3] = 0u;
    const bf16x8 zero8 = (bf16x8){0,0,0,0,0,0,0,0};
    bf16x8 x2 = (q == 0) ? rf.v : zero8;

    // ---- layer 1 (K=96, rel+bias folded) ----
    f32x4 acc[4];
    #pragma unroll
    for (int nt = 0; nt < 4; ++nt) acc[nt] = (f32x4){0.f,0.f,0.f,0.f};
    #pragma unroll
    for (int nt = 0; nt < 4; ++nt)
      acc[nt] = __builtin_amdgcn_mfma_f32_16x16x32_bf16(w1f[0][nt], xf0, acc[nt], 0,0,0);
    #pragma unroll
    for (int nt = 0; nt < 4; ++nt)
      acc[nt] = __builtin_amdgcn_mfma_f32_16x16x32_bf16(w1f[1][nt], xf1, acc[nt], 0,0,0);
    #pragma unroll
    for (int nt = 0; nt < 4; ++nt)
      acc[nt] = __builtin_amdgcn_mfma_f32_16x16x32_bf16(w1f[2][nt], x2,  acc[nt], 0,0,0);
    #pragma unroll
    for (int nt = 0; nt < 4; ++nt) {
      const int o = nt*16 + q*4;
      float v0 = fmaxf(acc[nt][0], 0.f), v1 = fmaxf(acc[nt][1], 0.f);
      float v2 = fmaxf(acc[nt][2], 0.f), v3 = fmaxf(acc[nt][3], 0.f);
      uint2 pk = { pk2bf(v0, v1), pk2bf(v2, v3) };
      *(uint2*)(myH + cl*72 + o) = pk;
    }

    // ---- layer 2 (W2 frags from LDS) ----
    bf16x8 hb0 = *(const bf16x8*)(myH + cl*72 + q*8);
    bf16x8 hb1 = *(const bf16x8*)(myH + cl*72 + 32 + q*8);
    #pragma unroll
    for (int nt = 0; nt < 4; ++nt) acc[nt] = (f32x4){0.f,0.f,0.f,0.f};
    #pragma unroll
    for (int nt = 0; nt < 4; ++nt) {
      bf16x8 wa = *(const bf16x8*)(sW2T + (nt*16+cl)*72 + q*8);
      acc[nt] = __builtin_amdgcn_mfma_f32_16x16x32_bf16(wa, hb0, acc[nt], 0,0,0);
    }
    #pragma unroll
    for (int nt = 0; nt < 4; ++nt) {
      bf16x8 wa = *(const bf16x8*)(sW2T + (nt*16+cl)*72 + 32 + q*8);
      acc[nt] = __builtin_amdgcn_mfma_f32_16x16x32_bf16(wa, hb1, acc[nt], 0,0,0);
    }
    #pragma unroll
    for (int nt = 0; nt < 4; ++nt) {
      const int o = nt*16 + q*4;
      f32x4 bb = *(const f32x4*)(sB2 + o);     // 16-lane broadcast
      float v0 = fmaxf(acc[nt][0] + bb[0], 0.f), v1 = fmaxf(acc[nt][1] + bb[1], 0.f);
      float v2 = fmaxf(acc[nt][2] + bb[2], 0.f), v3 = fmaxf(acc[nt][3] + bb[3], 0.f);
      uint2 pk = { pk2bf(v0, v1), pk2bf(v2, v3) };
      *(uint2*)(myH + cl*72 + o) = pk;
    }

    // ---- layer 3 (W3 frags in regs) + running max (b3 deferred) ----
    bf16x8 h20 = *(const bf16x8*)(myH + cl*72 + q*8);
    bf16x8 h21 = *(const bf16x8*)(myH + cl*72 + 32 + q*8);
    f32x4 acc3[8];
    #pragma unroll
    for (int nt = 0; nt < 8; ++nt) acc3[nt] = (f32x4){0.f,0.f,0.f,0.f};
    #pragma unroll
    for (int nt = 0; nt < 8; ++nt)
      acc3[nt] = __builtin_amdgcn_mfma_f32_16x16x32_bf16(w3f[0][nt], h20, acc3[nt], 0,0,0);
    #pragma unroll
    for (int nt = 0; nt < 8; ++nt)
      acc3[nt] = __builtin_amdgcn_mfma_f32_16x16x32_bf16(w3f[1][nt], h21, acc3[nt], 0,0,0);
    if (t*16 + 16 <= count) {                  // full strip (wave-uniform)
      #pragma unroll
      for (int nt = 0; nt < 8; ++nt)
        #pragma unroll
        for (int r = 0; r < 4; ++r)
          runmax[nt][r] = fmaxf(runmax[nt][r], acc3[nt][r]);
    } else {                                   // global last strip only
      const float vm = (t*16 + cl < count) ? 0.f : -__builtin_inff();
      #pragma unroll
      for (int nt = 0; nt < 8; ++nt)
        #pragma unroll
        for (int r = 0; r < 4; ++r)
          runmax[nt][r] = fmaxf(runmax[nt][r], acc3[nt][r] + vm);
    }

    // rotate pipeline
    c4 = c4n; xf0 = xf0n; xf1 = xf1n; p_nxt = p_nn;
  }

  // reduce over points (cl lanes), then across waves; write partials
  #pragma unroll
  for (int nt = 0; nt < 8; ++nt) {
    #pragma unroll
    for (int r = 0; r < 4; ++r) {
      float m = runmax[nt][r];
      m = fmaxf(m, __shfl_xor(m, 1));
      m = fmaxf(m, __shfl_xor(m, 2));
      m = fmaxf(m, __shfl_xor(m, 4));
      m = fmaxf(m, __shfl_xor(m, 8));
      runmax[nt][r] = m;
    }
    if (cl == 0) *(f32x4*)(sMax + w*128 + nt*16 + q*4) = runmax[nt];
  }
  __syncthreads();
  if (tid < 128) {
    float m = fmaxf(fmaxf(sMax[tid], sMax[128+tid]),
                    fmaxf(sMax[256+tid], sMax[384+tid]));
    pmax[bx*128 + tid] = m;
  }
}

// ---------------------------------------------------------------- combine
__global__ __launch_bounds__(256) void combine_kernel(
    const float* __restrict__ pmax, const float* __restrict__ b3,
    float* __restrict__ outF) {
  int i = blockIdx.x*256 + threadIdx.x;      // 131072 = 1024*128
  int kk = i >> 7, c = i & 127;
  float m = fmaxf(pmax[(2*kk)*128 + c], pmax[(2*kk+1)*128 + c]);
  outF[i] = fmaxf(m + b3[c], 0.f);
}

// ---------------------------------------------------------------- launch
extern "C" void kernel_launch(void* const* d_in, const int* in_sizes, int n_in,
                              void* d_out, int out_size, void* d_ws, size_t ws_size,
                              hipStream_t stream) {
  const float* coords   = (const float*)d_in[0];
  const float* features = (const float*)d_in[1];
  const int*   cidx     = (const int*)d_in[2];
  const float* W1 = (const float*)d_in[3];
  const float* b1 = (const float*)d_in[4];
  const float* W2 = (const float*)d_in[5];
  const float* b2 = (const float*)d_in[6];
  const float* W3 = (const float*)d_in[7];
  const float* b3 = (const float*)d_in[8];
  float* out = (float*)d_out;           // [0:3072) cent, [3072:) new_features

  char* ws = (char*)d_ws;
  // maskbuf [0, 13,107,200) ALIASES featsBF+coords4 — safe: maskbuild/scan
  // complete (stream-serial) before prep writes featsBF/coords4.
  u64* maskbuf            = (u64*)(ws + 0);
  unsigned short* featsBF = (unsigned short*)(ws + 0);           // 12,800,000
  f32x4* coords4          = (f32x4*)(ws + 12800000);             //  1,600,000
  int* idxbuf  = (int*)(ws + 14400000);                          //  4,194,304
  int* counts  = (int*)(ws + 18594304);                          //      4,096
  unsigned short* W1T = (unsigned short*)(ws + 18598400);        //     12,288
  unsigned short* W2T = (unsigned short*)(ws + 18610688);        //      9,216
  unsigned short* W3T = (unsigned short*)(ws + 18619904);        //     18,432
  float* pmax = (float*)(ws + 18638336);                         //  1,048,576

  maskbuild_kernel<<<dim3(NSEG, 32), 256, 0, stream>>>(coords, cidx, maskbuf);
  maskscan_kernel<<<256, 256, 0, stream>>>(maskbuf, idxbuf, counts);
  prep_kernel<<<3598, 256, 0, stream>>>(coords, features, cidx, W1, b1, W2, W3,
                                        featsBF, coords4, W1T, W2T, W3T, out);
  fused_kernel<<<2048, 256, 0, stream>>>(featsBF, coords4, out, idxbuf, counts,
                                         b2, W1T, W2T, W3T, pmax);
  combine_kernel<<<512, 256, 0, stream>>>(pmax, b3, out + 3072);
}

// Round 4
// 239.888 us; speedup vs baseline: 1.4025x; 1.2089x over previous
//
#include <hip/hip_runtime.h>
#include <hip/hip_bf16.h>

#define NPTS    100000
#define KCENT   1024
#define NSEG    391          // ceil(NPTS/256)
#define NWORDS  1564         // NSEG*4 words of 64 points
#define WSTRIDE 1600         // mask words per centroid (padded)
#define MB_BLKS (NSEG*32)    // 12512 maskbuild blocks

typedef __attribute__((ext_vector_type(8))) short bf16x8;   // 8 bf16 (4 VGPRs)
typedef __attribute__((ext_vector_type(4))) float f32x4;
typedef unsigned long long u64;

__device__ __forceinline__ unsigned short f2bf(float x) {
  union { float f; unsigned u; } v; v.f = x;
  unsigned r = v.u + 0x7FFFu + ((v.u >> 16) & 1u);   // RNE
  return (unsigned short)(r >> 16);
}
__device__ __forceinline__ unsigned pk2bf(float a, float b) {
  union { __hip_bfloat162 h; unsigned u; } cv;
  cv.h = __float22bfloat162_rn(make_float2(a, b));
  return cv.u;
}
__device__ __forceinline__ bf16x8 pack_bf8(f32x4 a, f32x4 b) {
  union { bf16x8 v; unsigned u[4]; } r;
  r.u[0] = pk2bf(a[0], a[1]); r.u[1] = pk2bf(a[2], a[3]);
  r.u[2] = pk2bf(b[0], b[1]); r.u[3] = pk2bf(b[2], b[3]);
  return r.v;
}

// ---------------------------------------------------------------- maskbuild + prep (fused, independent halves)
// blocks [0, MB_BLKS): ball mask via ballot, 32 centroids x 256 points/block.
// blocks [MB_BLKS, ...): prep — featsBF bf16, coords4, W1T(96,augmented:
//   k<64 feat rows, 64..66 rel rows, 67 b1), W2T/W3T(72), cent -> d_out.
__global__ __launch_bounds__(256) void build_prep_kernel(
    const float* __restrict__ coords, const float* __restrict__ features,
    const int* __restrict__ cidx, const float* __restrict__ W1,
    const float* __restrict__ b1, const float* __restrict__ W2,
    const float* __restrict__ W3, u64* __restrict__ maskbuf,
    unsigned short* __restrict__ featsBF, f32x4* __restrict__ coords4,
    unsigned short* __restrict__ W1T, unsigned short* __restrict__ W2T,
    unsigned short* __restrict__ W3T, float* __restrict__ outCent) {
  const int bid = blockIdx.x;
  const int tid = threadIdx.x;
  if (bid < MB_BLKS) {
    const int grp = bid / NSEG, seg = bid - grp*NSEG;
    __shared__ float sC[96];
    __shared__ float sCC[32];
    if (tid < 96) sC[tid] = coords[cidx[grp*32 + tid/3]*3 + tid%3];
    __syncthreads();
    if (tid < 32) {
      float x = sC[tid*3], y = sC[tid*3+1], z = sC[tid*3+2];
      sCC[tid] = __fadd_rn(__fadd_rn(__fmul_rn(x,x), __fmul_rn(y,y)), __fmul_rn(z,z));
    }
    const int p = seg*256 + tid;
    const bool inr = p < NPTS;
    float px = 0.f, py = 0.f, pz = 0.f;
    if (inr) { px = coords[p*3]; py = coords[p*3+1]; pz = coords[p*3+2]; }
    const float pp = __fadd_rn(__fadd_rn(__fmul_rn(px,px), __fmul_rn(py,py)), __fmul_rn(pz,pz));
    __syncthreads();
    const int lane = tid & 63, wid = tid >> 6;
    u64 myw = 0ull;
    #pragma unroll
    for (int ci = 0; ci < 32; ++ci) {
      float cx = sC[ci*3], cy = sC[ci*3+1], cz = sC[ci*3+2];
      float dt = __fadd_rn(__fadd_rn(__fmul_rn(cx,px), __fmul_rn(cy,py)), __fmul_rn(cz,pz));
      float d2 = __fsub_rn(__fadd_rn(sCC[ci], pp), __fmul_rn(2.0f, dt));
      bool sel = inr && (d2 <= 0.04f);
      u64 m = __ballot(sel);
      if (lane == ci) myw = m;
    }
    if (lane < 32)
      maskbuf[(u64)(grp*32 + lane)*WSTRIDE + seg*4 + wid] = myw;
    return;
  }
  int i = (bid - MB_BLKS) * 256 + tid;
  if (i < 800000) {                       // 8 feature floats -> bf16x8
    const f32x4* src = (const f32x4*)features + i*2;
    f32x4 f0 = src[0], f1 = src[1];
    union { bf16x8 v; uint4 u; } pk; pk.v = pack_bf8(f0, f1);
    ((uint4*)featsBF)[i] = pk.u;
    return;
  }
  i -= 800000;
  if (i < NPTS) {
    coords4[i] = (f32x4){coords[3*i], coords[3*i+1], coords[3*i+2], 0.f};
    return;
  }
  i -= NPTS;
  if (i < 6144) {                         // W1T augmented, stride 96
    int n = i / 96, kk = i - n*96;
    float v = 0.f;
    if (kk < 64)       v = W1[(3+kk)*64 + n];
    else if (kk < 67)  v = W1[(kk-64)*64 + n];
    else if (kk == 67) v = b1[n];
    W1T[n*96 + kk] = f2bf(v);
    return;
  }
  i -= 6144;
  if (i < 4608) { int n = i / 72, kk = i - n*72;
    W2T[n*72 + kk] = f2bf(kk < 64 ? W2[kk*64 + n] : 0.f); return; }
  i -= 4608;
  if (i < 9216) { int n = i / 72, kk = i - n*72;
    W3T[n*72 + kk] = f2bf(kk < 64 ? W3[kk*128 + n] : 0.f); return; }
  i -= 9216;
  if (i < KCENT) {
    int ci = cidx[i];
    outCent[i*3+0] = coords[ci*3+0];
    outCent[i*3+1] = coords[ci*3+1];
    outCent[i*3+2] = coords[ci*3+2];
  }
}

// ---------------------------------------------------------------- mask scan
// One wave per centroid: ordered compaction of first 1024 set bits.
__global__ __launch_bounds__(256) void maskscan_kernel(
    const u64* __restrict__ maskbuf, int* __restrict__ idxbuf,
    int* __restrict__ counts) {
  const int tid = threadIdx.x;
  const int lane = tid & 63;
  const int c = blockIdx.x*4 + (tid >> 6);
  const u64* M = maskbuf + (u64)c * WSTRIDE;
  int* out = idxbuf + (c << 10);
  int base = 0;
  u64 word = (lane < NWORDS) ? M[lane] : 0ull;
  for (int chunk = 0; chunk < 25; ++chunk) {
    u64 next = 0ull;
    int wn = (chunk+1)*64 + lane;
    if (chunk+1 < 25 && wn < NWORDS) next = M[wn];
    int pc = __popcll(word);
    int inc = pc;
    #pragma unroll
    for (int d = 1; d < 64; d <<= 1) {
      int t = __shfl_up(inc, d);
      if (lane >= d) inc += t;
    }
    int tot = __shfl(inc, 63);
    int pos = base + inc - pc;
    while (word != 0ull && pos < KCENT) {
      int b = __ffsll((unsigned long long)word) - 1;
      out[pos++] = chunk*4096 + lane*64 + b;
      word &= word - 1ull;
    }
    base += tot;
    if (base >= KCENT) break;    // uniform
    word = next;
  }
  if (lane == 0) counts[c] = base < KCENT ? base : KCENT;
}

// ---------------------------------------------------------------- fused MLP + maxpool
// 2 blocks/centroid, 4 waves each. Each wave processes TWO independent
// 16-point columns (A,B) per iteration for in-wave ILP: while column A waits
// on its LDS h round-trip, column B's MFMA burst issues. Weights W1/W3 in
// regs, W2 from LDS (read once per iteration, shared by A/B). Depth-2 idx /
// depth-1 data prefetch per pair. b3 + final relu deferred to combine.
__global__ __launch_bounds__(256, 2) void fused_kernel(
    const unsigned short* __restrict__ featsBF, const f32x4* __restrict__ coords4,
    const float* __restrict__ cent, const int* __restrict__ idxbuf,
    const int* __restrict__ counts, const float* __restrict__ b2v,
    const unsigned short* __restrict__ gW1T, const unsigned short* __restrict__ gW2T,
    const unsigned short* __restrict__ gW3T, float* __restrict__ pmax) {
  __shared__ __align__(16) unsigned short sW2T[64*72];
  __shared__ __align__(16) unsigned short sH[4*2*16*72];  // per-wave A/B h-bufs
  __shared__ float sB2[64];
  __shared__ float sMax[512];

  const int bx = blockIdx.x;
  const int k = bx >> 1, b = bx & 1;
  const int tid = threadIdx.x;
  const int w = tid >> 6, lane = tid & 63;
  const int q = lane >> 4, cl = lane & 15;

  for (int i = tid; i < 576; i += 256) ((uint4*)sW2T)[i] = ((const uint4*)gW2T)[i];
  if (tid < 64) sB2[tid] = b2v[tid];

  bf16x8 w1f[3][4], w3f[2][8];
  #pragma unroll
  for (int ks = 0; ks < 3; ++ks)
    #pragma unroll
    for (int nt = 0; nt < 4; ++nt)
      w1f[ks][nt] = *(const bf16x8*)(gW1T + (nt*16+cl)*96 + ks*32 + q*8);
  #pragma unroll
  for (int ks = 0; ks < 2; ++ks)
    #pragma unroll
    for (int nt = 0; nt < 8; ++nt)
      w3f[ks][nt] = *(const bf16x8*)(gW3T + (nt*16+cl)*72 + ks*32 + q*8);

  const int count = counts[k];
  const float cx = cent[k*3], cy = cent[k*3+1], cz = cent[k*3+2];
  unsigned short* myHA = sH + w*2304;
  unsigned short* myHB = myHA + 1152;
  const int kb = k << 10;
  __syncthreads();

  f32x4 runmax[8];
  #pragma unroll
  for (int i = 0; i < 8; ++i)
    runmax[i] = (f32x4){-__builtin_inff(), -__builtin_inff(),
                        -__builtin_inff(), -__builtin_inff()};

  const int nstrips = (count + 15) >> 4;
  const int npairs  = (nstrips + 1) >> 1;
  int pp = 2*w + b;

  // ---- pipeline preload: pair pp data; pair pp+8 idx ----
  int pA = 0, pB = 0;
  { int jA = 32*pp + cl;      if (jA < count) pA = idxbuf[kb + jA];
    int jB = 32*pp + 16 + cl; if (jB < count) pB = idxbuf[kb + jB]; }
  f32x4  c4A = coords4[pA], c4B = coords4[pB];
  bf16x8 xfA0 = *(const bf16x8*)(featsBF + pA*64 + q*8);
  bf16x8 xfA1 = *(const bf16x8*)(featsBF + pA*64 + 32 + q*8);
  bf16x8 xfB0 = *(const bf16x8*)(featsBF + pB*64 + q*8);
  bf16x8 xfB1 = *(const bf16x8*)(featsBF + pB*64 + 32 + q*8);
  int pA2 = 0, pB2 = 0;
  { int jA = 32*(pp+8) + cl;      if (jA < count) pA2 = idxbuf[kb + jA];
    int jB = 32*(pp+8) + 16 + cl; if (jB < count) pB2 = idxbuf[kb + jB]; }

  const bf16x8 zero8 = (bf16x8){0,0,0,0,0,0,0,0};

  for (; pp < npairs; pp += 8) {
    // prefetch: idx pair pp+16; data pair pp+8
    int pA3 = 0, pB3 = 0;
    { int jA = 32*(pp+16) + cl;      if (jA < count) pA3 = idxbuf[kb + jA];
      int jB = 32*(pp+16) + 16 + cl; if (jB < count) pB3 = idxbuf[kb + jB]; }
    f32x4  c4An = coords4[pA2], c4Bn = coords4[pB2];
    bf16x8 xfA0n = *(const bf16x8*)(featsBF + pA2*64 + q*8);
    bf16x8 xfA1n = *(const bf16x8*)(featsBF + pA2*64 + 32 + q*8);
    bf16x8 xfB0n = *(const bf16x8*)(featsBF + pB2*64 + q*8);
    bf16x8 xfB1n = *(const bf16x8*)(featsBF + pB2*64 + 32 + q*8);

    // rel/bias B-fragments (k=64..67: rx,ry,rz,1)
    union { bf16x8 v; unsigned u[4]; } rfA, rfB;
    rfA.u[0] = pk2bf(c4A[0]-cx, c4A[1]-cy); rfA.u[1] = pk2bf(c4A[2]-cz, 1.0f);
    rfA.u[2] = 0u; rfA.u[3] = 0u;
    rfB.u[0] = pk2bf(c4B[0]-cx, c4B[1]-cy); rfB.u[1] = pk2bf(c4B[2]-cz, 1.0f);
    rfB.u[2] = 0u; rfB.u[3] = 0u;
    bf16x8 x2A = (q == 0) ? rfA.v : zero8;
    bf16x8 x2B = (q == 0) ? rfB.v : zero8;

    // ---- layer 1, columns A and B (independent chains) ----
    {
      f32x4 accA[4], accB[4];
      #pragma unroll
      for (int nt = 0; nt < 4; ++nt) { accA[nt] = (f32x4){0.f,0.f,0.f,0.f};
                                       accB[nt] = (f32x4){0.f,0.f,0.f,0.f}; }
      #pragma unroll
      for (int nt = 0; nt < 4; ++nt) {
        accA[nt] = __builtin_amdgcn_mfma_f32_16x16x32_bf16(w1f[0][nt], xfA0, accA[nt], 0,0,0);
        accB[nt] = __builtin_amdgcn_mfma_f32_16x16x32_bf16(w1f[0][nt], xfB0, accB[nt], 0,0,0);
      }
      #pragma unroll
      for (int nt = 0; nt < 4; ++nt) {
        accA[nt] = __builtin_amdgcn_mfma_f32_16x16x32_bf16(w1f[1][nt], xfA1, accA[nt], 0,0,0);
        accB[nt] = __builtin_amdgcn_mfma_f32_16x16x32_bf16(w1f[1][nt], xfB1, accB[nt], 0,0,0);
      }
      #pragma unroll
      for (int nt = 0; nt < 4; ++nt) {
        accA[nt] = __builtin_amdgcn_mfma_f32_16x16x32_bf16(w1f[2][nt], x2A, accA[nt], 0,0,0);
        accB[nt] = __builtin_amdgcn_mfma_f32_16x16x32_bf16(w1f[2][nt], x2B, accB[nt], 0,0,0);
      }
      #pragma unroll
      for (int nt = 0; nt < 4; ++nt) {
        const int o = nt*16 + q*4;
        uint2 pkA = { pk2bf(fmaxf(accA[nt][0],0.f), fmaxf(accA[nt][1],0.f)),
                      pk2bf(fmaxf(accA[nt][2],0.f), fmaxf(accA[nt][3],0.f)) };
        *(uint2*)(myHA + cl*72 + o) = pkA;
        uint2 pkB = { pk2bf(fmaxf(accB[nt][0],0.f), fmaxf(accB[nt][1],0.f)),
                      pk2bf(fmaxf(accB[nt][2],0.f), fmaxf(accB[nt][3],0.f)) };
        *(uint2*)(myHB + cl*72 + o) = pkB;
      }
    }

    // ---- layer 2 (W2 frags from LDS, shared by A/B) ----
    {
      bf16x8 w2r[2][4];
      #pragma unroll
      for (int ks = 0; ks < 2; ++ks)
        #pragma unroll
        for (int nt = 0; nt < 4; ++nt)
          w2r[ks][nt] = *(const bf16x8*)(sW2T + (nt*16+cl)*72 + ks*32 + q*8);
      bf16x8 hA0 = *(const bf16x8*)(myHA + cl*72 + q*8);
      bf16x8 hA1 = *(const bf16x8*)(myHA + cl*72 + 32 + q*8);
      bf16x8 hB0 = *(const bf16x8*)(myHB + cl*72 + q*8);
      bf16x8 hB1 = *(const bf16x8*)(myHB + cl*72 + 32 + q*8);
      f32x4 accA[4], accB[4];
      #pragma unroll
      for (int nt = 0; nt < 4; ++nt) { accA[nt] = (f32x4){0.f,0.f,0.f,0.f};
                                       accB[nt] = (f32x4){0.f,0.f,0.f,0.f}; }
      #pragma unroll
      for (int nt = 0; nt < 4; ++nt) {
        accA[nt] = __builtin_amdgcn_mfma_f32_16x16x32_bf16(w2r[0][nt], hA0, accA[nt], 0,0,0);
        accB[nt] = __builtin_amdgcn_mfma_f32_16x16x32_bf16(w2r[0][nt], hB0, accB[nt], 0,0,0);
      }
      #pragma unroll
      for (int nt = 0; nt < 4; ++nt) {
        accA[nt] = __builtin_amdgcn_mfma_f32_16x16x32_bf16(w2r[1][nt], hA1, accA[nt], 0,0,0);
        accB[nt] = __builtin_amdgcn_mfma_f32_16x16x32_bf16(w2r[1][nt], hB1, accB[nt], 0,0,0);
      }
      #pragma unroll
      for (int nt = 0; nt < 4; ++nt) {
        const int o = nt*16 + q*4;
        f32x4 bb = *(const f32x4*)(sB2 + o);
        uint2 pkA = { pk2bf(fmaxf(accA[nt][0]+bb[0],0.f), fmaxf(accA[nt][1]+bb[1],0.f)),
                      pk2bf(fmaxf(accA[nt][2]+bb[2],0.f), fmaxf(accA[nt][3]+bb[3],0.f)) };
        *(uint2*)(myHA + cl*72 + o) = pkA;
        uint2 pkB = { pk2bf(fmaxf(accB[nt][0]+bb[0],0.f), fmaxf(accB[nt][1]+bb[1],0.f)),
                      pk2bf(fmaxf(accB[nt][2]+bb[2],0.f), fmaxf(accB[nt][3]+bb[3],0.f)) };
        *(uint2*)(myHB + cl*72 + o) = pkB;
      }
    }

    // ---- layer 3 + masked running max (bias deferred) ----
    const float vmA = (32*pp + cl      < count) ? 0.f : -__builtin_inff();
    const float vmB = (32*pp + 16 + cl < count) ? 0.f : -__builtin_inff();
    {
      bf16x8 hA0 = *(const bf16x8*)(myHA + cl*72 + q*8);
      bf16x8 hA1 = *(const bf16x8*)(myHA + cl*72 + 32 + q*8);
      f32x4 acc3[8];
      #pragma unroll
      for (int nt = 0; nt < 8; ++nt) acc3[nt] = (f32x4){0.f,0.f,0.f,0.f};
      #pragma unroll
      for (int nt = 0; nt < 8; ++nt)
        acc3[nt] = __builtin_amdgcn_mfma_f32_16x16x32_bf16(w3f[0][nt], hA0, acc3[nt], 0,0,0);
      #pragma unroll
      for (int nt = 0; nt < 8; ++nt)
        acc3[nt] = __builtin_amdgcn_mfma_f32_16x16x32_bf16(w3f[1][nt], hA1, acc3[nt], 0,0,0);
      #pragma unroll
      for (int nt = 0; nt < 8; ++nt)
        #pragma unroll
        for (int r = 0; r < 4; ++r)
          runmax[nt][r] = fmaxf(runmax[nt][r], acc3[nt][r] + vmA);
    }
    {
      bf16x8 hB0 = *(const bf16x8*)(myHB + cl*72 + q*8);
      bf16x8 hB1 = *(const bf16x8*)(myHB + cl*72 + 32 + q*8);
      f32x4 acc3[8];
      #pragma unroll
      for (int nt = 0; nt < 8; ++nt) acc3[nt] = (f32x4){0.f,0.f,0.f,0.f};
      #pragma unroll
      for (int nt = 0; nt < 8; ++nt)
        acc3[nt] = __builtin_amdgcn_mfma_f32_16x16x32_bf16(w3f[0][nt], hB0, acc3[nt], 0,0,0);
      #pragma unroll
      for (int nt = 0; nt < 8; ++nt)
        acc3[nt] = __builtin_amdgcn_mfma_f32_16x16x32_bf16(w3f[1][nt], hB1, acc3[nt], 0,0,0);
      #pragma unroll
      for (int nt = 0; nt < 8; ++nt)
        #pragma unroll
        for (int r = 0; r < 4; ++r)
          runmax[nt][r] = fmaxf(runmax[nt][r], acc3[nt][r] + vmB);
    }

    // rotate pipeline
    c4A = c4An; c4B = c4Bn;
    xfA0 = xfA0n; xfA1 = xfA1n; xfB0 = xfB0n; xfB1 = xfB1n;
    pA2 = pA3; pB2 = pB3;
  }

  // reduce over points (cl lanes), then across waves; write partials
  #pragma unroll
  for (int nt = 0; nt < 8; ++nt) {
    #pragma unroll
    for (int r = 0; r < 4; ++r) {
      float m = runmax[nt][r];
      m = fmaxf(m, __shfl_xor(m, 1));
      m = fmaxf(m, __shfl_xor(m, 2));
      m = fmaxf(m, __shfl_xor(m, 4));
      m = fmaxf(m, __shfl_xor(m, 8));
      runmax[nt][r] = m;
    }
    if (cl == 0) *(f32x4*)(sMax + w*128 + nt*16 + q*4) = runmax[nt];
  }
  __syncthreads();
  if (tid < 128) {
    float m = fmaxf(fmaxf(sMax[tid], sMax[128+tid]),
                    fmaxf(sMax[256+tid], sMax[384+tid]));
    pmax[bx*128 + tid] = m;
  }
}

// ---------------------------------------------------------------- combine
__global__ __launch_bounds__(256) void combine_kernel(
    const float* __restrict__ pmax, const float* __restrict__ b3,
    float* __restrict__ outF) {
  int i = blockIdx.x*256 + threadIdx.x;      // 131072 = 1024*128
  int kk = i >> 7, c = i & 127;
  float m = fmaxf(pmax[(2*kk)*128 + c], pmax[(2*kk+1)*128 + c]);
  outF[i] = fmaxf(m + b3[c], 0.f);
}

// ---------------------------------------------------------------- launch
extern "C" void kernel_launch(void* const* d_in, const int* in_sizes, int n_in,
                              void* d_out, int out_size, void* d_ws, size_t ws_size,
                              hipStream_t stream) {
  const float* coords   = (const float*)d_in[0];
  const float* features = (const float*)d_in[1];
  const int*   cidx     = (const int*)d_in[2];
  const float* W1 = (const float*)d_in[3];
  const float* b1 = (const float*)d_in[4];
  const float* W2 = (const float*)d_in[5];
  const float* b2 = (const float*)d_in[6];
  const float* W3 = (const float*)d_in[7];
  const float* b3 = (const float*)d_in[8];
  float* out = (float*)d_out;           // [0:3072) cent, [3072:) new_features

  char* ws = (char*)d_ws;
  // De-aliased: maskbuild and prep now run concurrently in one launch.
  u64* maskbuf            = (u64*)(ws + 0);                      // 13,107,200
  unsigned short* featsBF = (unsigned short*)(ws + 13107200);    // 12,800,000
  f32x4* coords4          = (f32x4*)(ws + 25907200);             //  1,600,000
  int* idxbuf  = (int*)(ws + 27507200);                          //  4,194,304
  int* counts  = (int*)(ws + 31701504);                          //      4,096
  unsigned short* W1T = (unsigned short*)(ws + 31705600);        //     12,288
  unsigned short* W2T = (unsigned short*)(ws + 31717888);        //      9,216
  unsigned short* W3T = (unsigned short*)(ws + 31727104);        //     18,432
  float* pmax = (float*)(ws + 31745536);                         //  1,048,576

  build_prep_kernel<<<MB_BLKS + 3598, 256, 0, stream>>>(
      coords, features, cidx, W1, b1, W2, W3,
      maskbuf, featsBF, coords4, W1T, W2T, W3T, out);
  maskscan_kernel<<<256, 256, 0, stream>>>(maskbuf, idxbuf, counts);
  fused_kernel<<<2048, 256, 0, stream>>>(featsBF, coords4, out, idxbuf, counts,
                                         b2, W1T, W2T, W3T, pmax);
  combine_kernel<<<512, 256, 0, stream>>>(pmax, b3, out + 3072);
}